// Round 1
// 273.205 us; speedup vs baseline: 1.1014x; 1.1014x over previous
//
#include <hip/hip_runtime.h>

// GCNConv(100k nodes, 1M edges, D=128) + two heads (128->64), fp32 in/out.
// R9: final GEMM moved to MFMA fp16 (f32_16x16x32_f16), no LDS, B from a
// pre-transposed fp16 WfT resident in L1/L2; gather now emits fp16 aggh
// (halves its write traffic + halves final-GEMM read traffic).
// Pipeline: prep(fuse|convert|countA) -> scanA -> scanB -> scatter -> node
//           -> gather(bf16 in, fp16 out) -> MFMA final GEMM.

#define BLOCK 256
#define SB 512          // scatter blocks (pass A/C)
#define NB_MAX 784      // max coarse buckets (n<=100352)
#define CONV_BLOCKS 4096

typedef _Float16 half8 __attribute__((ext_vector_type(8)));
typedef _Float16 half2v __attribute__((ext_vector_type(2)));
typedef float f32x4 __attribute__((ext_vector_type(4)));

__device__ inline unsigned short f2bf(float f) {
    unsigned u = __float_as_uint(f);
    unsigned r = (u + 0x7FFF + ((u >> 16) & 1)) >> 16;  // RNE
    return (unsigned short)r;
}
__device__ inline float bf2f(unsigned short u) {
    return __uint_as_float(((unsigned)u) << 16);
}

// ---------------- prep: weight fusion (transposed fp16) | x->bf16 | pass A ----------------

__global__ __launch_bounds__(BLOCK) void k_prep(const float* __restrict__ x,
                                                const int* __restrict__ dst, int E,
                                                const float* __restrict__ Wg,
                                                const float* __restrict__ Wh,
                                                const float* __restrict__ Wl,
                                                const float* __restrict__ bg,
                                                const float* __restrict__ bh,
                                                const float* __restrict__ bl,
                                                _Float16* __restrict__ WfT,
                                                float* __restrict__ bf,
                                                int* __restrict__ hist_g,
                                                unsigned short* __restrict__ xh,
                                                int n, int NB) {
    __shared__ int hist[NB_MAX];
    int b = blockIdx.x;
    if (b < 16) {  // Wf = Wg @ [Wh|Wl], stored transposed as fp16: WfT[c][k]
        int r = b * 8 + (threadIdx.x >> 5);
        int c0 = (threadIdx.x & 31) * 4;
        float a0 = 0.f, a1 = 0.f, a2 = 0.f, a3 = 0.f;
        for (int j = 0; j < 128; j++) {
            float wg = Wg[r * 128 + j];
            float4 wc;
            if (c0 < 64) wc = *(const float4*)(Wh + j * 64 + c0);
            else         wc = *(const float4*)(Wl + j * 64 + (c0 - 64));
            a0 += wg * wc.x; a1 += wg * wc.y; a2 += wg * wc.z; a3 += wg * wc.w;
        }
        WfT[(size_t)(c0 + 0) * 128 + r] = (_Float16)a0;
        WfT[(size_t)(c0 + 1) * 128 + r] = (_Float16)a1;
        WfT[(size_t)(c0 + 2) * 128 + r] = (_Float16)a2;
        WfT[(size_t)(c0 + 3) * 128 + r] = (_Float16)a3;
    } else if (b == 16) {  // bf = bg @ [Wh|Wl] + [bh|bl]  (kept fp32)
        int c = threadIdx.x;
        if (c < 128) {
            float acc = (c < 64) ? bh[c] : bl[c - 64];
            for (int j = 0; j < 128; j++) {
                float wc = (c < 64) ? Wh[j * 64 + c] : Wl[j * 64 + (c - 64)];
                acc += bg[j] * wc;
            }
            bf[c] = acc;
        }
    } else if (b < 17 + SB) {  // pass A: LDS bucket histogram of this block's chunk
        int blk = b - 17;
        for (int i = threadIdx.x; i < NB; i += BLOCK) hist[i] = 0;
        __syncthreads();
        int chunk = (E + SB - 1) / SB;
        int e0 = blk * chunk, e1 = min(E, e0 + chunk);
        for (int e = e0 + threadIdx.x; e < e1; e += BLOCK)
            atomicAdd(&hist[dst[e] >> 7], 1);
        __syncthreads();
        for (int i = threadIdx.x; i < NB; i += BLOCK)
            hist_g[(size_t)i * SB + blk] = hist[i];
    } else {  // x -> bf16
        const float4* x4 = (const float4*)x;
        ushort4* o4 = (ushort4*)xh;
        int total = n * 32;
        int i = (b - 17 - SB) * BLOCK + threadIdx.x;
        int stride = CONV_BLOCKS * BLOCK;
        for (; i < total; i += stride) {
            float4 v = x4[i];
            ushort4 o;
            o.x = f2bf(v.x); o.y = f2bf(v.y); o.z = f2bf(v.z); o.w = f2bf(v.w);
            o4[i] = o;
        }
    }
}

// ---------------- scan A: per-bucket exclusive prefix over SB blocks ----------------

__global__ __launch_bounds__(BLOCK) void k_scanA(int* __restrict__ hist_g,
                                                 int* __restrict__ bucketTotal, int NB) {
    __shared__ int s[SB];
    int bkt = blockIdx.x;
    int t = threadIdx.x;
    int a0 = hist_g[(size_t)bkt * SB + t];
    int a1 = hist_g[(size_t)bkt * SB + t + 256];
    s[t] = a0; s[t + 256] = a1;
    __syncthreads();
    for (int ofs = 1; ofs < SB; ofs <<= 1) {
        int v0 = (t >= ofs) ? s[t - ofs] : 0;
        int v1 = (t + 256 >= ofs) ? s[t + 256 - ofs] : 0;
        __syncthreads();
        s[t] += v0; s[t + 256] += v1;
        __syncthreads();
    }
    hist_g[(size_t)bkt * SB + t] = s[t] - a0;              // exclusive
    hist_g[(size_t)bkt * SB + t + 256] = s[t + 256] - a1;
    if (t == 255) bucketTotal[bkt] = s[SB - 1];
}

// ---------------- scan B: exclusive scan over buckets ----------------

__global__ __launch_bounds__(1024) void k_scanB(const int* __restrict__ bucketTotal,
                                                int* __restrict__ bucketStart,
                                                int NB, int E) {
    __shared__ int s[1024];
    int t = threadIdx.x;
    int v = (t < NB) ? bucketTotal[t] : 0;
    s[t] = v;
    __syncthreads();
    for (int ofs = 1; ofs < 1024; ofs <<= 1) {
        int u = (t >= ofs) ? s[t - ofs] : 0;
        __syncthreads();
        s[t] += u;
        __syncthreads();
    }
    if (t < NB) bucketStart[t] = s[t] - v;
    if (t == NB - 1) bucketStart[NB] = E;
}

// ---------------- pass C: scatter edges into bucket-grouped ebuf ----------------

__global__ __launch_bounds__(BLOCK) void k_scatter(const int* __restrict__ src,
                                                   const int* __restrict__ dst, int E,
                                                   const int* __restrict__ hist_g,
                                                   const int* __restrict__ bucketStart,
                                                   int2* __restrict__ ebuf, int NB) {
    __shared__ int cur[NB_MAX];
    int blk = blockIdx.x;
    for (int i = threadIdx.x; i < NB; i += BLOCK)
        cur[i] = bucketStart[i] + hist_g[(size_t)i * SB + blk];
    __syncthreads();
    int chunk = (E + SB - 1) / SB;
    int e0 = blk * chunk, e1 = min(E, e0 + chunk);
    for (int e = e0 + threadIdx.x; e < e1; e += BLOCK) {
        int d = dst[e];
        int pos = atomicAdd(&cur[d >> 7], 1);  // LDS atomic
        ebuf[pos] = make_int2(d, src[e]);
    }
}

// ---------------- pass D: per-bucket fine sort -> compact CSR + dinv ----------------

__global__ __launch_bounds__(BLOCK) void k_node(const int2* __restrict__ ebuf,
                                                const int* __restrict__ bucketStart,
                                                int* __restrict__ off,
                                                float* __restrict__ dinv,
                                                int* __restrict__ csr,
                                                int n, int NB, int E) {
    __shared__ int cnt[128];
    __shared__ int pre[128];
    __shared__ int cur[128];
    int bkt = blockIdx.x;
    int t = threadIdx.x;
    int node0 = bkt << 7;
    int nn = min(128, n - node0);
    int eb0 = bucketStart[bkt], eb1 = bucketStart[bkt + 1];

    if (t < 128) cnt[t] = 0;
    __syncthreads();
    for (int e = eb0 + t; e < eb1; e += BLOCK)
        atomicAdd(&cnt[ebuf[e].x & 127], 1);
    __syncthreads();
    if (t < 128) pre[t] = cnt[t];
    __syncthreads();
    for (int ofs = 1; ofs < 128; ofs <<= 1) {
        int v = (t < 128 && t >= ofs) ? pre[t - ofs] : 0;
        __syncthreads();
        if (t < 128) pre[t] += v;
        __syncthreads();
    }
    if (t < 128) cur[t] = pre[t] - cnt[t];
    __syncthreads();
    if (t < nn) {
        off[node0 + t] = eb0 + cur[t];
        dinv[node0 + t] = rsqrtf((float)(cnt[t] + 1));
    }
    if (bkt == 0 && t == 0) off[n] = E;
    for (int e = eb0 + t; e < eb1; e += BLOCK) {
        int2 p = ebuf[e];
        int pos = atomicAdd(&cur[p.x & 127], 1);  // LDS atomic
        csr[eb0 + pos] = p.y;
    }
}

// ---------------- gather: aggh[d] = fp16( dv*sum(dinv[s]*x[s]) + dv^2*x[d] ) ----------------

__global__ __launch_bounds__(BLOCK) void k_gather(const int* __restrict__ off,
                                                  const int* __restrict__ csr,
                                                  const float* __restrict__ dinv,
                                                  const unsigned short* __restrict__ xh,
                                                  const float* __restrict__ x,
                                                  _Float16* __restrict__ aggh, int n) {
    int wave = (blockIdx.x * blockDim.x + threadIdx.x) >> 6;
    int lane = threadIdx.x & 63;
    if (wave >= n) return;
    int d = wave;
    int beg = off[d], end = off[d + 1];

    float accx = 0.f, accy = 0.f;
    for (int base = beg; base < end; base += 64) {
        int cnt = min(64, end - base);
        int s = 0; float w = 0.f;
        if (lane < cnt) { s = csr[base + lane]; w = dinv[s]; }
        int j = 0;
        for (; j + 4 <= cnt; j += 4) {
            int s0 = __shfl(s, j);
            int s1 = __shfl(s, j + 1);
            int s2 = __shfl(s, j + 2);
            int s3 = __shfl(s, j + 3);
            float w0 = __shfl(w, j);
            float w1 = __shfl(w, j + 1);
            float w2 = __shfl(w, j + 2);
            float w3 = __shfl(w, j + 3);
            ushort2 v0 = ((const ushort2*)(xh + (size_t)s0 * 128))[lane];
            ushort2 v1 = ((const ushort2*)(xh + (size_t)s1 * 128))[lane];
            ushort2 v2 = ((const ushort2*)(xh + (size_t)s2 * 128))[lane];
            ushort2 v3 = ((const ushort2*)(xh + (size_t)s3 * 128))[lane];
            accx += w0 * bf2f(v0.x) + w1 * bf2f(v1.x) + w2 * bf2f(v2.x) + w3 * bf2f(v3.x);
            accy += w0 * bf2f(v0.y) + w1 * bf2f(v1.y) + w2 * bf2f(v2.y) + w3 * bf2f(v3.y);
        }
        for (; j < cnt; j++) {
            int sj = __shfl(s, j);
            float wj = __shfl(w, j);
            ushort2 v = ((const ushort2*)(xh + (size_t)sj * 128))[lane];
            accx += wj * bf2f(v.x);
            accy += wj * bf2f(v.y);
        }
    }
    float dv = dinv[d];
    float2 xv = ((const float2*)(x + (size_t)d * 128))[lane];  // self-loop fp32
    half2v o;
    o.x = (_Float16)(dv * accx + dv * dv * xv.x);
    o.y = (_Float16)(dv * accy + dv * dv * xv.y);
    ((half2v*)(aggh + (size_t)d * 128))[lane] = o;
}

// ---------------- final GEMM via MFMA fp16: out = aggh @ WfT^T + bf ----------------
// Block = 256 thr = 4 waves; block tile 128 rows x 128 cols; wave = 32 rows x 128 cols.
// A frag: row = lane&15, k = 8*(lane>>4)+i  -> contiguous 16B from aggh.
// B frag: col = lane&15, k = 8*(lane>>4)+i  -> contiguous 16B from WfT[c][k] (L1-resident, 32KB).
// C/D:    col = lane&15, row = 4*(lane>>4)+j.

__global__ __launch_bounds__(BLOCK) void k_final(const _Float16* __restrict__ aggh,
                                                 const _Float16* __restrict__ WfT,
                                                 const float* __restrict__ bf,
                                                 float* __restrict__ out, int n) {
    int wave = threadIdx.x >> 6;          // 0..3
    int lane = threadIdx.x & 63;
    int l15 = lane & 15;
    int lk = lane >> 4;                   // 0..3
    int row_base = blockIdx.x * 128 + wave * 32;

    // Load all A fragments up front: 2 row-frags x 4 K-steps, 16B each.
    half8 a[2][4];
#pragma unroll
    for (int rf = 0; rf < 2; rf++) {
        int r = row_base + rf * 16 + l15;
        if (r >= n) r = n - 1;
        const _Float16* ap = aggh + (size_t)r * 128 + lk * 8;
#pragma unroll
        for (int kk = 0; kk < 4; kk++)
            a[rf][kk] = *(const half8*)(ap + kk * 32);
    }

    f32x4 acc[2][8];
#pragma unroll
    for (int rf = 0; rf < 2; rf++)
#pragma unroll
        for (int cf = 0; cf < 8; cf++)
            acc[rf][cf] = (f32x4){0.f, 0.f, 0.f, 0.f};

#pragma unroll
    for (int kk = 0; kk < 4; kk++) {
#pragma unroll
        for (int cf = 0; cf < 8; cf++) {
            const _Float16* bp = WfT + (size_t)(cf * 16 + l15) * 128 + kk * 32 + lk * 8;
            half8 bfr = *(const half8*)bp;
#pragma unroll
            for (int rf = 0; rf < 2; rf++)
                acc[rf][cf] = __builtin_amdgcn_mfma_f32_16x16x32_f16(
                    a[rf][kk], bfr, acc[rf][cf], 0, 0, 0);
        }
    }

    // Epilogue: bias + split high/low store.
#pragma unroll
    for (int cf = 0; cf < 8; cf++) {
        int c = cf * 16 + l15;
        float bv = bf[c];
        size_t cbase = (c < 64) ? (size_t)c : (size_t)n * 64 + (size_t)(c - 64);
#pragma unroll
        for (int rf = 0; rf < 2; rf++) {
            int r0 = row_base + rf * 16 + lk * 4;
#pragma unroll
            for (int j = 0; j < 4; j++) {
                int r = r0 + j;
                if (r < n) out[cbase + (size_t)r * 64] = acc[rf][cf][j] + bv;
            }
        }
    }
}

extern "C" void kernel_launch(void* const* d_in, const int* in_sizes, int n_in,
                              void* d_out, int out_size, void* d_ws, size_t ws_size,
                              hipStream_t stream) {
    const float* x  = (const float*)d_in[0];
    const int*   ei = (const int*)d_in[1];
    const float* Wg = (const float*)d_in[2];
    const float* bg = (const float*)d_in[3];
    const float* Wh = (const float*)d_in[4];
    const float* bh = (const float*)d_in[5];
    const float* Wl = (const float*)d_in[6];
    const float* bl = (const float*)d_in[7];
    float* out = (float*)d_out;

    int n = in_sizes[0] / 128;
    int E = in_sizes[1] / 2;
    const int* src = ei;
    const int* dst = ei + E;
    int NB = (n + 127) >> 7;

    char* ws = (char*)d_ws;
    int*   hist_g      = (int*)ws;                ws += (size_t)NB_MAX * SB * 4;
    int*   bucketTotal = (int*)ws;                ws += (size_t)NB_MAX * 4;
    int*   bucketStart = (int*)ws;                ws += (size_t)(NB_MAX + 2) * 4;  // +2 keeps ebuf 8B-aligned
    int2*  ebuf        = (int2*)ws;               ws += (size_t)E * 8;
    int*   off         = (int*)ws;                ws += (size_t)(n + 1) * 4;
    float* dinv        = (float*)ws;              ws += (size_t)n * 4;
    int*   csr         = (int*)ws;                ws += (size_t)E * 4;
    _Float16* aggh     = (_Float16*)ws;           ws += (size_t)n * 128 * 2;
    _Float16* WfT      = (_Float16*)ws;           ws += (size_t)128 * 128 * 2;
    float* bf          = (float*)ws;              ws += (size_t)128 * 4;
    unsigned short* xh = (unsigned short*)ws;

    k_prep<<<17 + SB + CONV_BLOCKS, BLOCK, 0, stream>>>(
        x, dst, E, Wg, Wh, Wl, bg, bh, bl, WfT, bf, hist_g, xh, n, NB);
    k_scanA<<<NB, BLOCK, 0, stream>>>(hist_g, bucketTotal, NB);
    k_scanB<<<1, 1024, 0, stream>>>(bucketTotal, bucketStart, NB, E);
    k_scatter<<<SB, BLOCK, 0, stream>>>(src, dst, E, hist_g, bucketStart, ebuf, NB);
    k_node<<<NB, BLOCK, 0, stream>>>(ebuf, bucketStart, off, dinv, csr, n, NB, E);
    k_gather<<<((size_t)n * 64 + BLOCK - 1) / BLOCK, BLOCK, 0, stream>>>(
        off, csr, dinv, xh, x, aggh, n);
    k_final<<<(n + 127) / 128, BLOCK, 0, stream>>>(aggh, WfT, bf, out, n);
}

// Round 2
// 259.377 us; speedup vs baseline: 1.1601x; 1.0533x over previous
//
#include <hip/hip_runtime.h>

// GCNConv(100k nodes, 1M edges, D=128) + two heads (128->64), fp32 in/out.
// R10: gather restructured for ILP — 4 edges/wave-iter, 16B/lane loads,
// fp16 xh everywhere (v_fma_mix folds cvt into FMA; self-loop also from xh,
// killing the fp32 x re-read). Final GEMM stays MFMA fp16. Workspace
// buffers 256B-aligned.
// Pipeline: prep(fuse|convert fp16|countA) -> scanA -> scanB -> scatter
//           -> node -> gather(fp16) -> MFMA final GEMM.

#define BLOCK 256
#define SB 512          // scatter blocks (pass A/C)
#define NB_MAX 784      // max coarse buckets (n<=100352)
#define CONV_BLOCKS 4096

typedef _Float16 half8 __attribute__((ext_vector_type(8)));
typedef _Float16 half4 __attribute__((ext_vector_type(4)));
typedef float f32x4 __attribute__((ext_vector_type(4)));

// ---------------- prep: weight fusion (transposed fp16) | x->fp16 | pass A ----------------

__global__ __launch_bounds__(BLOCK) void k_prep(const float* __restrict__ x,
                                                const int* __restrict__ dst, int E,
                                                const float* __restrict__ Wg,
                                                const float* __restrict__ Wh,
                                                const float* __restrict__ Wl,
                                                const float* __restrict__ bg,
                                                const float* __restrict__ bh,
                                                const float* __restrict__ bl,
                                                _Float16* __restrict__ WfT,
                                                float* __restrict__ bf,
                                                int* __restrict__ hist_g,
                                                _Float16* __restrict__ xh,
                                                int n, int NB) {
    __shared__ int hist[NB_MAX];
    int b = blockIdx.x;
    if (b < 16) {  // Wf = Wg @ [Wh|Wl], stored transposed as fp16: WfT[c][k]
        int r = b * 8 + (threadIdx.x >> 5);
        int c0 = (threadIdx.x & 31) * 4;
        float a0 = 0.f, a1 = 0.f, a2 = 0.f, a3 = 0.f;
        for (int j = 0; j < 128; j++) {
            float wg = Wg[r * 128 + j];
            float4 wc;
            if (c0 < 64) wc = *(const float4*)(Wh + j * 64 + c0);
            else         wc = *(const float4*)(Wl + j * 64 + (c0 - 64));
            a0 += wg * wc.x; a1 += wg * wc.y; a2 += wg * wc.z; a3 += wg * wc.w;
        }
        WfT[(size_t)(c0 + 0) * 128 + r] = (_Float16)a0;
        WfT[(size_t)(c0 + 1) * 128 + r] = (_Float16)a1;
        WfT[(size_t)(c0 + 2) * 128 + r] = (_Float16)a2;
        WfT[(size_t)(c0 + 3) * 128 + r] = (_Float16)a3;
    } else if (b == 16) {  // bf = bg @ [Wh|Wl] + [bh|bl]  (kept fp32)
        int c = threadIdx.x;
        if (c < 128) {
            float acc = (c < 64) ? bh[c] : bl[c - 64];
            for (int j = 0; j < 128; j++) {
                float wc = (c < 64) ? Wh[j * 64 + c] : Wl[j * 64 + (c - 64)];
                acc += bg[j] * wc;
            }
            bf[c] = acc;
        }
    } else if (b < 17 + SB) {  // pass A: LDS bucket histogram of this block's chunk
        int blk = b - 17;
        for (int i = threadIdx.x; i < NB; i += BLOCK) hist[i] = 0;
        __syncthreads();
        int chunk = (E + SB - 1) / SB;
        int e0 = blk * chunk, e1 = min(E, e0 + chunk);
        for (int e = e0 + threadIdx.x; e < e1; e += BLOCK)
            atomicAdd(&hist[dst[e] >> 7], 1);
        __syncthreads();
        for (int i = threadIdx.x; i < NB; i += BLOCK)
            hist_g[(size_t)i * SB + blk] = hist[i];
    } else {  // x -> fp16
        const float4* x4 = (const float4*)x;
        half4* o4 = (half4*)xh;
        int total = n * 32;
        int i = (b - 17 - SB) * BLOCK + threadIdx.x;
        int stride = CONV_BLOCKS * BLOCK;
        for (; i < total; i += stride) {
            float4 v = x4[i];
            half4 o;
            o.x = (_Float16)v.x; o.y = (_Float16)v.y;
            o.z = (_Float16)v.z; o.w = (_Float16)v.w;
            o4[i] = o;
        }
    }
}

// ---------------- scan A: per-bucket exclusive prefix over SB blocks ----------------

__global__ __launch_bounds__(BLOCK) void k_scanA(int* __restrict__ hist_g,
                                                 int* __restrict__ bucketTotal, int NB) {
    __shared__ int s[SB];
    int bkt = blockIdx.x;
    int t = threadIdx.x;
    int a0 = hist_g[(size_t)bkt * SB + t];
    int a1 = hist_g[(size_t)bkt * SB + t + 256];
    s[t] = a0; s[t + 256] = a1;
    __syncthreads();
    for (int ofs = 1; ofs < SB; ofs <<= 1) {
        int v0 = (t >= ofs) ? s[t - ofs] : 0;
        int v1 = (t + 256 >= ofs) ? s[t + 256 - ofs] : 0;
        __syncthreads();
        s[t] += v0; s[t + 256] += v1;
        __syncthreads();
    }
    hist_g[(size_t)bkt * SB + t] = s[t] - a0;              // exclusive
    hist_g[(size_t)bkt * SB + t + 256] = s[t + 256] - a1;
    if (t == 255) bucketTotal[bkt] = s[SB - 1];
}

// ---------------- scan B: exclusive scan over buckets ----------------

__global__ __launch_bounds__(1024) void k_scanB(const int* __restrict__ bucketTotal,
                                                int* __restrict__ bucketStart,
                                                int NB, int E) {
    __shared__ int s[1024];
    int t = threadIdx.x;
    int v = (t < NB) ? bucketTotal[t] : 0;
    s[t] = v;
    __syncthreads();
    for (int ofs = 1; ofs < 1024; ofs <<= 1) {
        int u = (t >= ofs) ? s[t - ofs] : 0;
        __syncthreads();
        s[t] += u;
        __syncthreads();
    }
    if (t < NB) bucketStart[t] = s[t] - v;
    if (t == NB - 1) bucketStart[NB] = E;
}

// ---------------- pass C: scatter edges into bucket-grouped ebuf ----------------

__global__ __launch_bounds__(BLOCK) void k_scatter(const int* __restrict__ src,
                                                   const int* __restrict__ dst, int E,
                                                   const int* __restrict__ hist_g,
                                                   const int* __restrict__ bucketStart,
                                                   int2* __restrict__ ebuf, int NB) {
    __shared__ int cur[NB_MAX];
    int blk = blockIdx.x;
    for (int i = threadIdx.x; i < NB; i += BLOCK)
        cur[i] = bucketStart[i] + hist_g[(size_t)i * SB + blk];
    __syncthreads();
    int chunk = (E + SB - 1) / SB;
    int e0 = blk * chunk, e1 = min(E, e0 + chunk);
    for (int e = e0 + threadIdx.x; e < e1; e += BLOCK) {
        int d = dst[e];
        int pos = atomicAdd(&cur[d >> 7], 1);  // LDS atomic
        ebuf[pos] = make_int2(d, src[e]);
    }
}

// ---------------- pass D: per-bucket fine sort -> compact CSR + dinv ----------------

__global__ __launch_bounds__(BLOCK) void k_node(const int2* __restrict__ ebuf,
                                                const int* __restrict__ bucketStart,
                                                int* __restrict__ off,
                                                float* __restrict__ dinv,
                                                int* __restrict__ csr,
                                                int n, int NB, int E) {
    __shared__ int cnt[128];
    __shared__ int pre[128];
    __shared__ int cur[128];
    int bkt = blockIdx.x;
    int t = threadIdx.x;
    int node0 = bkt << 7;
    int nn = min(128, n - node0);
    int eb0 = bucketStart[bkt], eb1 = bucketStart[bkt + 1];

    if (t < 128) cnt[t] = 0;
    __syncthreads();
    for (int e = eb0 + t; e < eb1; e += BLOCK)
        atomicAdd(&cnt[ebuf[e].x & 127], 1);
    __syncthreads();
    if (t < 128) pre[t] = cnt[t];
    __syncthreads();
    for (int ofs = 1; ofs < 128; ofs <<= 1) {
        int v = (t < 128 && t >= ofs) ? pre[t - ofs] : 0;
        __syncthreads();
        if (t < 128) pre[t] += v;
        __syncthreads();
    }
    if (t < 128) cur[t] = pre[t] - cnt[t];
    __syncthreads();
    if (t < nn) {
        off[node0 + t] = eb0 + cur[t];
        dinv[node0 + t] = rsqrtf((float)(cnt[t] + 1));
    }
    if (bkt == 0 && t == 0) off[n] = E;
    for (int e = eb0 + t; e < eb1; e += BLOCK) {
        int2 p = ebuf[e];
        int pos = atomicAdd(&cur[p.x & 127], 1);  // LDS atomic
        csr[eb0 + pos] = p.y;
    }
}

// ---------------- gather: aggh[d] = fp16( dv*(sum(dinv[s]*x[s]) + dv*x[d]) ) ----------------
// One wave per node. 4 edges per iteration: group g = lane>>4 picks edge,
// slice sl = lane&15 reads 16B (8 fp16 feats). Partial sums reduced across
// groups with two shfl_xor at the end.

__global__ __launch_bounds__(BLOCK) void k_gather(const int* __restrict__ off,
                                                  const int* __restrict__ csr,
                                                  const float* __restrict__ dinv,
                                                  const _Float16* __restrict__ xh,
                                                  _Float16* __restrict__ aggh, int n) {
    int wave = (blockIdx.x * blockDim.x + threadIdx.x) >> 6;
    int lane = threadIdx.x & 63;
    if (wave >= n) return;
    int d = wave;
    int beg = off[d], end = off[d + 1];
    int g = lane >> 4;        // edge sub-group 0..3
    int sl = lane & 15;       // 16B slice of the 256B row

    float acc[8];
#pragma unroll
    for (int k = 0; k < 8; k++) acc[k] = 0.f;

    for (int base = beg; base < end; base += 64) {
        int cnt = min(64, end - base);
        int s = 0; float w = 0.f;
        if (lane < cnt) { s = csr[base + lane]; w = dinv[s]; }
        for (int j = 0; j < cnt; j += 4) {
            int e = j + g;                 // e<64; e>=cnt lanes carry w=0,s=0 (safe)
            int se = __shfl(s, e);
            float we = __shfl(w, e);
            half8 v = *(const half8*)(xh + (size_t)se * 128 + sl * 8);
#pragma unroll
            for (int k = 0; k < 8; k++)
                acc[k] += we * (float)v[k];   // v_fma_mix_f32
        }
    }

    // reduce the 4 edge-groups: each lane ends with full sum for its slice
#pragma unroll
    for (int k = 0; k < 8; k++) {
        acc[k] += __shfl_xor(acc[k], 16);
        acc[k] += __shfl_xor(acc[k], 32);
    }

    float dv = dinv[d];
    half8 xv = *(const half8*)(xh + (size_t)d * 128 + sl * 8);  // self-loop (fp16)
    half8 o;
#pragma unroll
    for (int k = 0; k < 8; k++)
        o[k] = (_Float16)(dv * (acc[k] + dv * (float)xv[k]));
    if (lane < 16)
        *(half8*)(aggh + (size_t)d * 128 + sl * 8) = o;
}

// ---------------- final GEMM via MFMA fp16: out = aggh @ WfT^T + bf ----------------
// Block = 256 thr = 4 waves; block tile 128 rows x 128 cols; wave = 32 rows x 128 cols.
// A frag: row = lane&15, k = 8*(lane>>4)+i  -> contiguous 16B from aggh.
// B frag: col = lane&15, k = 8*(lane>>4)+i  -> contiguous 16B from WfT[c][k] (L1-resident, 32KB).
// C/D:    col = lane&15, row = 4*(lane>>4)+j.

__global__ __launch_bounds__(BLOCK) void k_final(const _Float16* __restrict__ aggh,
                                                 const _Float16* __restrict__ WfT,
                                                 const float* __restrict__ bf,
                                                 float* __restrict__ out, int n) {
    int wave = threadIdx.x >> 6;          // 0..3
    int lane = threadIdx.x & 63;
    int l15 = lane & 15;
    int lk = lane >> 4;                   // 0..3
    int row_base = blockIdx.x * 128 + wave * 32;

    // Load all A fragments up front: 2 row-frags x 4 K-steps, 16B each.
    half8 a[2][4];
#pragma unroll
    for (int rf = 0; rf < 2; rf++) {
        int r = row_base + rf * 16 + l15;
        if (r >= n) r = n - 1;
        const _Float16* ap = aggh + (size_t)r * 128 + lk * 8;
#pragma unroll
        for (int kk = 0; kk < 4; kk++)
            a[rf][kk] = *(const half8*)(ap + kk * 32);
    }

    f32x4 acc[2][8];
#pragma unroll
    for (int rf = 0; rf < 2; rf++)
#pragma unroll
        for (int cf = 0; cf < 8; cf++)
            acc[rf][cf] = (f32x4){0.f, 0.f, 0.f, 0.f};

#pragma unroll
    for (int kk = 0; kk < 4; kk++) {
#pragma unroll
        for (int cf = 0; cf < 8; cf++) {
            const _Float16* bp = WfT + (size_t)(cf * 16 + l15) * 128 + kk * 32 + lk * 8;
            half8 bfr = *(const half8*)bp;
#pragma unroll
            for (int rf = 0; rf < 2; rf++)
                acc[rf][cf] = __builtin_amdgcn_mfma_f32_16x16x32_f16(
                    a[rf][kk], bfr, acc[rf][cf], 0, 0, 0);
        }
    }

    // Epilogue: bias + split high/low store.
#pragma unroll
    for (int cf = 0; cf < 8; cf++) {
        int c = cf * 16 + l15;
        float bv = bf[c];
        size_t cbase = (c < 64) ? (size_t)c : (size_t)n * 64 + (size_t)(c - 64);
#pragma unroll
        for (int rf = 0; rf < 2; rf++) {
            int r0 = row_base + rf * 16 + lk * 4;
#pragma unroll
            for (int j = 0; j < 4; j++) {
                int r = r0 + j;
                if (r < n) out[cbase + (size_t)r * 64] = acc[rf][cf][j] + bv;
            }
        }
    }
}

extern "C" void kernel_launch(void* const* d_in, const int* in_sizes, int n_in,
                              void* d_out, int out_size, void* d_ws, size_t ws_size,
                              hipStream_t stream) {
    const float* x  = (const float*)d_in[0];
    const int*   ei = (const int*)d_in[1];
    const float* Wg = (const float*)d_in[2];
    const float* bg = (const float*)d_in[3];
    const float* Wh = (const float*)d_in[4];
    const float* bh = (const float*)d_in[5];
    const float* Wl = (const float*)d_in[6];
    const float* bl = (const float*)d_in[7];
    float* out = (float*)d_out;

    int n = in_sizes[0] / 128;
    int E = in_sizes[1] / 2;
    const int* src = ei;
    const int* dst = ei + E;
    int NB = (n + 127) >> 7;

#define WS_TAKE(ptr, type, count)                                        \
    ptr = (type*)wsp;                                                    \
    wsp = (char*)(((size_t)(wsp + (size_t)(count) * sizeof(type)) + 255) \
                  & ~(size_t)255)

    char* wsp = (char*)d_ws;
    int*      hist_g;      WS_TAKE(hist_g,      int,      (size_t)NB_MAX * SB);
    int*      bucketTotal; WS_TAKE(bucketTotal, int,      NB_MAX);
    int*      bucketStart; WS_TAKE(bucketStart, int,      NB_MAX + 1);
    int2*     ebuf;        WS_TAKE(ebuf,        int2,     E);
    int*      off;         WS_TAKE(off,         int,      n + 1);
    float*    dinv;        WS_TAKE(dinv,        float,    n);
    int*      csr;         WS_TAKE(csr,         int,      E);
    _Float16* aggh;        WS_TAKE(aggh,        _Float16, (size_t)n * 128);
    _Float16* WfT;         WS_TAKE(WfT,         _Float16, 128 * 128);
    float*    bf;          WS_TAKE(bf,          float,    128);
    _Float16* xh;          WS_TAKE(xh,          _Float16, (size_t)n * 128);

    k_prep<<<17 + SB + CONV_BLOCKS, BLOCK, 0, stream>>>(
        x, dst, E, Wg, Wh, Wl, bg, bh, bl, WfT, bf, hist_g, xh, n, NB);
    k_scanA<<<NB, BLOCK, 0, stream>>>(hist_g, bucketTotal, NB);
    k_scanB<<<1, 1024, 0, stream>>>(bucketTotal, bucketStart, NB, E);
    k_scatter<<<SB, BLOCK, 0, stream>>>(src, dst, E, hist_g, bucketStart, ebuf, NB);
    k_node<<<NB, BLOCK, 0, stream>>>(ebuf, bucketStart, off, dinv, csr, n, NB, E);
    k_gather<<<((size_t)n * 64 + BLOCK - 1) / BLOCK, BLOCK, 0, stream>>>(
        off, csr, dinv, xh, aggh, n);
    k_final<<<(n + 127) / 128, BLOCK, 0, stream>>>(aggh, WfT, bf, out, n);
}

// Round 3
// 244.692 us; speedup vs baseline: 1.2298x; 1.0600x over previous
//
#include <hip/hip_runtime.h>

// GCNConv(100k nodes, 1M edges, D=128) + two heads (128->64), fp32 in/out.
// R11: pipeline restructure 7 -> 4 kernels.
//  - k_prep: weight fusion (fp16 WfT) | bias | cursor init | x->fp16
//  - k_scatter: single-pass bucket scatter via LDS stash + LDS hist +
//    per-(block,bucket) global atomic range reservation into fixed 2048-entry
//    slots (replaces passA/scanA/scanB/old-scatter; kills 25MB strided reads)
//  - k_node: per-bucket counting sort -> csr + off2{beg,end} + dinv
//  - k_gf: FUSED gather+GEMM. 4 nodes/wave (16 lanes each), broadcast
//    csr/dinv loads (no shuffles), unroll-4 row loads for MLP; 64-row tile
//    staged in XOR-swizzled LDS (wave-local, no barrier), then MFMA fp16
//    final GEMM + bias + split store. Kills the 50MB aggh round-trip.

#define BLOCK 256
#define SB 512           // scatter blocks
#define NB_MAX 784       // max coarse buckets (n<=100352)
#define SLOT 2048        // per-bucket ebuf/csr capacity (avg 1280, max ~1400)
#define CHUNK_MAX 2048   // per-scatter-block edge stash (E <= SB*CHUNK_MAX)
#define CONV_BLOCKS 4096

typedef _Float16 half8 __attribute__((ext_vector_type(8)));
typedef _Float16 half4 __attribute__((ext_vector_type(4)));
typedef float f32x4 __attribute__((ext_vector_type(4)));

// ---------------- prep: Wf fusion (fp16, transposed) | bias+cursor | x->fp16 ----------------

__global__ __launch_bounds__(BLOCK) void k_prep(const float* __restrict__ x,
                                                const float* __restrict__ Wg,
                                                const float* __restrict__ Wh,
                                                const float* __restrict__ Wl,
                                                const float* __restrict__ bg,
                                                const float* __restrict__ bh,
                                                const float* __restrict__ bl,
                                                _Float16* __restrict__ WfT,
                                                float* __restrict__ bf,
                                                int* __restrict__ cursor,
                                                _Float16* __restrict__ xh,
                                                int n, int NB) {
    int b = blockIdx.x;
    if (b < 16) {  // Wf = Wg @ [Wh|Wl], stored transposed as fp16: WfT[c][k]
        int r = b * 8 + (threadIdx.x >> 5);
        int c0 = (threadIdx.x & 31) * 4;
        float a0 = 0.f, a1 = 0.f, a2 = 0.f, a3 = 0.f;
        for (int j = 0; j < 128; j++) {
            float wg = Wg[r * 128 + j];
            float4 wc;
            if (c0 < 64) wc = *(const float4*)(Wh + j * 64 + c0);
            else         wc = *(const float4*)(Wl + j * 64 + (c0 - 64));
            a0 += wg * wc.x; a1 += wg * wc.y; a2 += wg * wc.z; a3 += wg * wc.w;
        }
        WfT[(size_t)(c0 + 0) * 128 + r] = (_Float16)a0;
        WfT[(size_t)(c0 + 1) * 128 + r] = (_Float16)a1;
        WfT[(size_t)(c0 + 2) * 128 + r] = (_Float16)a2;
        WfT[(size_t)(c0 + 3) * 128 + r] = (_Float16)a3;
    } else if (b == 16) {  // bias fusion + bucket cursor init
        int c = threadIdx.x;
        if (c < 128) {
            float acc = (c < 64) ? bh[c] : bl[c - 64];
            for (int j = 0; j < 128; j++) {
                float wc = (c < 64) ? Wh[j * 64 + c] : Wl[j * 64 + (c - 64)];
                acc += bg[j] * wc;
            }
            bf[c] = acc;
        }
        for (int i = threadIdx.x; i < NB; i += BLOCK) cursor[i] = i * SLOT;
    } else {  // x -> fp16
        const float4* x4 = (const float4*)x;
        half4* o4 = (half4*)xh;
        int total = n * 32;
        int i = (b - 17) * BLOCK + threadIdx.x;
        int stride = CONV_BLOCKS * BLOCK;
        for (; i < total; i += stride) {
            float4 v = x4[i];
            half4 o;
            o.x = (_Float16)v.x; o.y = (_Float16)v.y;
            o.z = (_Float16)v.z; o.w = (_Float16)v.w;
            o4[i] = o;
        }
    }
}

// ---------------- scatter: stash chunk in LDS, LDS hist, atomic range reserve ----------------

__global__ __launch_bounds__(BLOCK) void k_scatter(const int* __restrict__ src,
                                                   const int* __restrict__ dst, int E,
                                                   int* __restrict__ cursor,
                                                   int2* __restrict__ ebuf, int NB) {
    __shared__ int2 stash[CHUNK_MAX];
    __shared__ int hist[NB_MAX];
    __shared__ int cur[NB_MAX];
    int blk = blockIdx.x;
    int chunk = (E + SB - 1) / SB;                 // <= CHUNK_MAX
    int e0 = blk * chunk, e1 = min(E, e0 + chunk);
    int m = e1 - e0;

    for (int i = threadIdx.x; i < NB; i += BLOCK) hist[i] = 0;
    __syncthreads();
    for (int i = threadIdx.x; i < m; i += BLOCK) {
        int d = dst[e0 + i], s = src[e0 + i];
        stash[i] = make_int2(d, s);
        atomicAdd(&hist[d >> 7], 1);
    }
    __syncthreads();
    for (int i = threadIdx.x; i < NB; i += BLOCK) {
        int h = hist[i];
        cur[i] = h ? atomicAdd(&cursor[i], h) : 0;  // reserve [base, base+h)
    }
    __syncthreads();
    for (int i = threadIdx.x; i < m; i += BLOCK) {
        int2 p = stash[i];
        int pos = atomicAdd(&cur[p.x >> 7], 1);     // LDS cursor
        ebuf[pos] = p;
    }
}

// ---------------- node: per-bucket counting sort -> csr + off2 + dinv ----------------

__global__ __launch_bounds__(BLOCK) void k_node(const int2* __restrict__ ebuf,
                                                const int* __restrict__ cursor,
                                                int2* __restrict__ off2,
                                                float* __restrict__ dinv,
                                                int* __restrict__ csr,
                                                int n) {
    __shared__ int cnt[128];
    __shared__ int pre[128];
    __shared__ int cur[128];
    int bkt = blockIdx.x;
    int t = threadIdx.x;
    int node0 = bkt << 7;
    int nn = min(128, n - node0);
    int eb0 = bkt * SLOT;
    int eb1 = cursor[bkt];                          // cursor after scatter = end

    if (t < 128) cnt[t] = 0;
    __syncthreads();
    for (int e = eb0 + t; e < eb1; e += BLOCK)
        atomicAdd(&cnt[ebuf[e].x & 127], 1);
    __syncthreads();
    if (t < 128) pre[t] = cnt[t];
    __syncthreads();
    for (int ofs = 1; ofs < 128; ofs <<= 1) {
        int v = (t < 128 && t >= ofs) ? pre[t - ofs] : 0;
        __syncthreads();
        if (t < 128) pre[t] += v;
        __syncthreads();
    }
    if (t < 128) cur[t] = pre[t] - cnt[t];          // exclusive
    __syncthreads();
    if (t < nn) {
        off2[node0 + t] = make_int2(eb0 + cur[t], eb0 + pre[t]);
        dinv[node0 + t] = rsqrtf((float)(cnt[t] + 1));
    }
    for (int e = eb0 + t; e < eb1; e += BLOCK) {
        int2 p = ebuf[e];
        int pos = atomicAdd(&cur[p.x & 127], 1);    // LDS atomic
        csr[eb0 + pos] = p.y;
    }
}

// ---------------- fused gather + MFMA final GEMM ----------------
// Block = 256 thr = 4 waves, tile = 64 nodes (wave w owns rows w*16..w*16+16).
// Gather: 4 passes; in each pass group g (lane>>4) owns node tile0+w*16+p*4+g,
// lane sl (lane&15) owns the 16B feature slice. csr/dinv are 16-lane
// same-address broadcast loads; edge loop unrolled x4 for MLP. Result rows go
// to XOR-swizzled LDS (chunk ^ (row&7)) -- wave-local, so no barrier.
// GEMM: A-frags from LDS (row=lane&15, chunk=kk*4+lk, swizzled -> conflict-free),
// B-frags 16B contiguous from fp16 WfT[c][k] (L2-resident), bias + split store.

__global__ __launch_bounds__(BLOCK) void k_gf(const int2* __restrict__ off2,
                                              const int* __restrict__ csr,
                                              const float* __restrict__ dinv,
                                              const _Float16* __restrict__ xh,
                                              const _Float16* __restrict__ WfT,
                                              const float* __restrict__ bf,
                                              float* __restrict__ out, int n) {
    __shared__ _Float16 lds[64 * 128];              // 16KB tile
    int wave = threadIdx.x >> 6;
    int lane = threadIdx.x & 63;
    int g = lane >> 4;                              // node sub-group / k-block
    int sl = lane & 15;                             // 16B slice / row-in-frag
    int T0 = blockIdx.x * 64;
    int wrow0 = wave * 16;

    // ---- gather phase: 16 nodes per wave, 4 per pass ----
    for (int p = 0; p < 4; p++) {
        int r = wrow0 + p * 4 + g;                  // row in tile, 0..63
        int d = T0 + r;
        int dc = min(d, n - 1);
        bool valid = (d < n);
        int2 oe = off2[dc];                         // broadcast 8B
        float dv = valid ? dinv[dc] : 0.f;
        int beg = oe.x;
        int end = valid ? oe.y : oe.x;
        half8 xv = *(const half8*)(xh + (size_t)dc * 128 + sl * 8);
        float acc[8];
#pragma unroll
        for (int k = 0; k < 8; k++) acc[k] = dv * (float)xv[k];   // self-loop

        int e = beg;
        for (; e + 4 <= end; e += 4) {
            int s0 = csr[e], s1 = csr[e + 1], s2 = csr[e + 2], s3 = csr[e + 3];
            float w0 = dinv[s0], w1 = dinv[s1], w2 = dinv[s2], w3 = dinv[s3];
            half8 v0 = *(const half8*)(xh + (size_t)s0 * 128 + sl * 8);
            half8 v1 = *(const half8*)(xh + (size_t)s1 * 128 + sl * 8);
            half8 v2 = *(const half8*)(xh + (size_t)s2 * 128 + sl * 8);
            half8 v3 = *(const half8*)(xh + (size_t)s3 * 128 + sl * 8);
#pragma unroll
            for (int k = 0; k < 8; k++)
                acc[k] += w0 * (float)v0[k] + w1 * (float)v1[k]
                        + w2 * (float)v2[k] + w3 * (float)v3[k];
        }
        for (; e < end; ++e) {
            int s0 = csr[e];
            float w0 = dinv[s0];
            half8 v0 = *(const half8*)(xh + (size_t)s0 * 128 + sl * 8);
#pragma unroll
            for (int k = 0; k < 8; k++) acc[k] += w0 * (float)v0[k];
        }
        half8 o;
#pragma unroll
        for (int k = 0; k < 8; k++) o[k] = (_Float16)(dv * acc[k]);
        *(half8*)(lds + (size_t)r * 128 + ((sl ^ (r & 7)) * 8)) = o;
    }

    // ---- GEMM phase (wave-local rows; compiler inserts lgkmcnt wait) ----
    int l15 = sl, lk = g;
    half8 a[4];
    {
        int r = wrow0 + l15;
#pragma unroll
        for (int kk = 0; kk < 4; kk++) {
            int ch = (kk * 4 + lk) ^ (l15 & 7);
            a[kk] = *(const half8*)(lds + (size_t)r * 128 + ch * 8);
        }
    }
    f32x4 acc[8];
#pragma unroll
    for (int cf = 0; cf < 8; cf++) acc[cf] = (f32x4){0.f, 0.f, 0.f, 0.f};
#pragma unroll
    for (int kk = 0; kk < 4; kk++) {
#pragma unroll
        for (int cf = 0; cf < 8; cf++) {
            half8 bfr = *(const half8*)(WfT + (size_t)(cf * 16 + l15) * 128 + kk * 32 + lk * 8);
            acc[cf] = __builtin_amdgcn_mfma_f32_16x16x32_f16(a[kk], bfr, acc[cf], 0, 0, 0);
        }
    }
#pragma unroll
    for (int cf = 0; cf < 8; cf++) {
        int c = cf * 16 + l15;
        float bv = bf[c];
        size_t cbase = (c < 64) ? (size_t)c : (size_t)n * 64 + (size_t)(c - 64);
        int r0 = T0 + wrow0 + lk * 4;
#pragma unroll
        for (int j = 0; j < 4; j++) {
            int rr = r0 + j;
            if (rr < n) out[cbase + (size_t)rr * 64] = acc[cf][j] + bv;
        }
    }
}

extern "C" void kernel_launch(void* const* d_in, const int* in_sizes, int n_in,
                              void* d_out, int out_size, void* d_ws, size_t ws_size,
                              hipStream_t stream) {
    const float* x  = (const float*)d_in[0];
    const int*   ei = (const int*)d_in[1];
    const float* Wg = (const float*)d_in[2];
    const float* bg = (const float*)d_in[3];
    const float* Wh = (const float*)d_in[4];
    const float* bh = (const float*)d_in[5];
    const float* Wl = (const float*)d_in[6];
    const float* bl = (const float*)d_in[7];
    float* out = (float*)d_out;

    int n = in_sizes[0] / 128;
    int E = in_sizes[1] / 2;
    const int* src = ei;
    const int* dst = ei + E;
    int NB = (n + 127) >> 7;

#define WS_TAKE(ptr, type, count)                                        \
    ptr = (type*)wsp;                                                    \
    wsp = (char*)(((size_t)(wsp + (size_t)(count) * sizeof(type)) + 255) \
                  & ~(size_t)255)

    char* wsp = (char*)d_ws;
    int*      cursor; WS_TAKE(cursor, int,      NB_MAX);
    int2*     ebuf;   WS_TAKE(ebuf,   int2,     (size_t)NB_MAX * SLOT);
    int2*     off2;   WS_TAKE(off2,   int2,     n);
    float*    dinv;   WS_TAKE(dinv,   float,    n);
    int*      csr;    WS_TAKE(csr,    int,      (size_t)NB_MAX * SLOT);
    _Float16* WfT;    WS_TAKE(WfT,    _Float16, 128 * 128);
    float*    bf;     WS_TAKE(bf,     float,    128);
    _Float16* xh;     WS_TAKE(xh,     _Float16, (size_t)n * 128);

    k_prep<<<17 + CONV_BLOCKS, BLOCK, 0, stream>>>(
        x, Wg, Wh, Wl, bg, bh, bl, WfT, bf, cursor, xh, n, NB);
    k_scatter<<<SB, BLOCK, 0, stream>>>(src, dst, E, cursor, ebuf, NB);
    k_node<<<NB, BLOCK, 0, stream>>>(ebuf, cursor, off2, dinv, csr, n);
    k_gf<<<(n + 63) / 64, BLOCK, 0, stream>>>(off2, csr, dinv, xh, WfT, bf, out, n);
}